// Round 7
// baseline (193.459 us; speedup 1.0000x reference)
//
#include <hip/hip_runtime.h>
#include <hip/hip_bf16.h>
#include <math.h>

// CerberusSemanticIDBranch — fused prototype-softmax-affinity kernel for MI355X.
//
// out[r,g,:] = (e_g @ M'_g) / sum(e_g),  e_k = exp(l_k - max_g),
// l_k = (x_r . Pn_k) / ((||x_r||+1e-6) * tau),  Pn_k = P_k/(||P_k||+1e-6),
// M'_g = A_g @ P_g / (rowsum(A_g)+1e-6)   (rowsum(A) is constant per group).
//
// Round 7: same math as round 6 (both matmuls bf16 MFMA, phase-2 B block-
// diagonal so zeros mask cross-group terms, template<G> keeps fragment
// indices compile-time). Occupancy fix: round 6's grid (512 blocks x 8
// waves) = 4096 waves = only 16 waves/CU (grid-capped at 50%). Now blocks
// of 16 rows x 256 threads (4 waves), grid 2048 -> 8192 waves = 32/CU
// (100% cap); per-wave work halves (phase 1: 2 col-tiles, phase 2: 40
// tiles). LDS ~8.8 KB, launch_bounds(256,8) -> VGPR <= 64.

constexpr int D    = 512;
constexpr int KTOT = 121;
constexpr int KP   = 128;   // padded k for phase-2 B
constexpr float TAU = 0.07f;

constexpr int GB[5]  = {0, 2, 17, 57, 97};   // group base row in concat [121] layout
constexpr int GK[5]  = {2, 15, 40, 40, 24};  // prototypes per group
constexpr int GD2[5] = {1, 3, 5, 5, 4};      // second attribute cardinality
constexpr int GNA[5] = {1, 2, 2, 2, 2};      // number of attributes
constexpr int KS0[5] = {0, 0, 0, 1, 3};      // first live 32-wide kstep of group
constexpr int KS1[5] = {1, 1, 2, 4, 4};      // one past last live kstep

using f32x4 = __attribute__((ext_vector_type(4))) float;
using s16x8 = __attribute__((ext_vector_type(8))) short;

__device__ __forceinline__ const float* pick(int k,
    const float* P0, const float* P1, const float* P2, const float* P3, const float* P4,
    int* kl) {
  if (k < 2)  { *kl = k;      return P0; }
  if (k < 17) { *kl = k - 2;  return P1; }
  if (k < 57) { *kl = k - 17; return P2; }
  if (k < 97) { *kl = k - 57; return P3; }
  *kl = k - 97; return P4;
}

__device__ __forceinline__ short f2bf(float f) {
  __hip_bfloat16 h = __float2bfloat16(f);   // RTNE
  return *reinterpret_cast<short*>(&h);
}

// ---- prep 1: inverse norms of the 121 prototype rows --------------------
__global__ void prep_norms(const float* __restrict__ P0, const float* __restrict__ P1,
                           const float* __restrict__ P2, const float* __restrict__ P3,
                           const float* __restrict__ P4, float* __restrict__ invn) {
  int k = blockIdx.x;  // 0..120
  int kl; const float* P = pick(k, P0, P1, P2, P3, P4, &kl);
  const float* row = P + (size_t)kl * D;
  float s = 0.f;
  for (int d = threadIdx.x; d < D; d += 64) { float v = row[d]; s += v * v; }
  #pragma unroll
  for (int m = 1; m < 64; m <<= 1) s += __shfl_xor(s, m);
  if (threadIdx.x == 0) invn[k] = 1.f / (sqrtf(s) + 1e-6f);
}

// ---- prep 2: pnb[c][k] = bf16(Pn[c][k]), rows 121..127 zero -------------
__global__ void prep_pnb(const float* __restrict__ P0, const float* __restrict__ P1,
                         const float* __restrict__ P2, const float* __restrict__ P3,
                         const float* __restrict__ P4, const float* __restrict__ invn,
                         unsigned short* __restrict__ pnb) {
  int idx = blockIdx.x * 256 + threadIdx.x;  // 128*512 = 65536
  int c = idx >> 9, k = idx & (D - 1);
  float v = 0.f;
  if (c < KTOT) {
    int kl; const float* P = pick(c, P0, P1, P2, P3, P4, &kl);
    v = P[(size_t)kl * D + k] * invn[c];
  }
  pnb[idx] = (unsigned short)f2bf(v);
}

// ---- prep 3: mptb[gd][kp] = bf16 block-diagonal (A@P/rowsum)^T ----------
// gd = g*512 + d (output column), kp = global k. Nonzero only for
// kp in [GB[g], GB[g]+GK[g]); value = M'_g[kp-GB[g]][d].
__global__ void prep_mpt(const float* __restrict__ P0, const float* __restrict__ P1,
                         const float* __restrict__ P2, const float* __restrict__ P3,
                         const float* __restrict__ P4, unsigned short* __restrict__ mptb) {
  int idx = blockIdx.x * 256 + threadIdx.x;  // 2560*128 = 327680
  int gd = idx >> 7, kp = idx & (KP - 1);
  int g = gd >> 9, d = gd & (D - 1);
  float v = 0.f;
  if (kp >= GB[g] && kp < GB[g] + GK[g]) {
    int kl = kp - GB[g];
    const float* P = (g == 0) ? P0 : (g == 1) ? P1 : (g == 2) ? P2 : (g == 3) ? P3 : P4;
    int d2 = GD2[g], na = GNA[g], K = GK[g];
    int a1 = kl / d2, a2 = kl % d2;
    float s = 0.f, m = 0.f;
    for (int j = 0; j < K; j++) {
      float aff;
      if (na == 1) {
        aff = (j == kl) ? 1.f : 0.f;
      } else {
        int b1 = j / d2, b2 = j % d2;
        aff = 0.5f * (float)((a1 == b1) + (a2 == b2));
      }
      s += aff;
      m += aff * P[(size_t)j * D + d];
    }
    v = m / (s + 1e-6f);
  }
  mptb[idx] = (unsigned short)f2bf(v);
}

// ---- phase 2 per-group body: all fragment indices compile-time ----------
template <int G>
__device__ __forceinline__ void phase2_group(
    const s16x8 (&af2)[4], const unsigned short* __restrict__ mptb,
    float* __restrict__ obase, int w, int lane15, int ko) {
  // group G owns output columns [G*512, G*512+512) -> 32 col-tiles of 16;
  // this wave takes the 8 tiles with (tile & 3) == w.
  #pragma unroll 1
  for (int i = 0; i < 8; ++i) {
    const int gd0 = G * 512 + (((i << 2) | w) << 4);
    f32x4 acc2 = (f32x4){0.f, 0.f, 0.f, 0.f};
    const unsigned short* bp = mptb + (size_t)(gd0 + lane15) * KP + ko;
    #pragma unroll
    for (int s = KS0[G]; s < KS1[G]; ++s) {   // constexpr bounds -> af2[s] static
      s16x8 bfv = *(const s16x8*)(bp + s * 32);
      acc2 = __builtin_amdgcn_mfma_f32_16x16x32_bf16(af2[s], bfv, acc2, 0, 0, 0);
    }
    float* op = obase + gd0;
    op[0]            = acc2[0];
    op[5 * D]        = acc2[1];
    op[2 * (5 * D)]  = acc2[2];
    op[3 * (5 * D)]  = acc2[3];
  }
}

// ---- main fused kernel --------------------------------------------------
// 2048 blocks x 256 threads (4 waves); block owns 16 rows. Phase 1: wave w
// computes logit cols [32w, 32w+32) for all 16 rows (16 ksteps x 2 MFMA).
// Phase 2: wave w takes col-tiles with parity w (40 tiles).
__global__ __launch_bounds__(256, 8) void fused_main(
    const float* __restrict__ x, const unsigned short* __restrict__ pnb,
    const unsigned short* __restrict__ mptb, float* __restrict__ out) {
  __shared__ float lred[KP][17];   // [k][row], pad-17; cols 121..127 stay 0
  __shared__ float xsqs[16];       // ||x||^2 per block-row

  const int tid    = threadIdx.x;
  const int lane   = tid & 63;
  const int w      = __builtin_amdgcn_readfirstlane(tid >> 6);
  const int lane15 = lane & 15;
  const int ko     = (lane >> 4) << 3;
  const int r0     = blockIdx.x * 16;

  // ---- phase 1: 16x32 logit slice via MFMA, K = 512 ----
  {
    const float* xrow = x + (size_t)(r0 + lane15) * D + ko;

    f32x4 acc[2];
    acc[0] = (f32x4){0.f, 0.f, 0.f, 0.f};
    acc[1] = (f32x4){0.f, 0.f, 0.f, 0.f};
    float xsq = 0.f;

    #pragma unroll 4
    for (int s = 0; s < 16; ++s) {
      float4 a0 = *(const float4*)(xrow + s * 32);
      float4 a1 = *(const float4*)(xrow + s * 32 + 4);
      if (w == 0)
        xsq += a0.x * a0.x + a0.y * a0.y + a0.z * a0.z + a0.w * a0.w
             + a1.x * a1.x + a1.y * a1.y + a1.z * a1.z + a1.w * a1.w;
      s16x8 af;
      af[0] = f2bf(a0.x); af[1] = f2bf(a0.y); af[2] = f2bf(a0.z); af[3] = f2bf(a0.w);
      af[4] = f2bf(a1.x); af[5] = f2bf(a1.y); af[6] = f2bf(a1.z); af[7] = f2bf(a1.w);
      #pragma unroll
      for (int t = 0; t < 2; ++t) {
        const int col = (w << 5) + (t << 4) + lane15;
        s16x8 bfv = *(const s16x8*)(pnb + (size_t)col * D + s * 32 + ko);
        acc[t] = __builtin_amdgcn_mfma_f32_16x16x32_bf16(af, bfv, acc[t], 0, 0, 0);
      }
    }

    if (w == 0) {
      // lanes {l, l^16, l^32, l^48} share the same A-row
      xsq += __shfl_xor(xsq, 16);
      xsq += __shfl_xor(xsq, 32);
      if (lane < 16) xsqs[lane] = xsq;
    }

    // dump C-frags: col = lane15, row = (lane>>4)*4 + j
    const int drow = (lane >> 4) << 2;
    #pragma unroll
    for (int t = 0; t < 2; ++t) {
      const int col = (w << 5) + (t << 4) + lane15;
      #pragma unroll
      for (int j = 0; j < 4; ++j) lred[col][drow + j] = acc[t][j];
    }
  }
  __syncthreads();

  // ---- softmax (wave 0: groups 0,1; waves 1-3: groups 2,3,4), lane = row --
  if (lane < 16) {
    const float scale = 1.f / ((sqrtf(xsqs[lane]) + 1e-6f) * TAU);
    const int gfirst = (w == 0) ? 0 : (w + 1);
    const int glast  = (w == 0) ? 1 : (w + 1);
    for (int g = gfirst; g <= glast; ++g) {
      float mx = -1e30f;
      for (int kk = 0; kk < GK[g]; ++kk)
        mx = fmaxf(mx, lred[GB[g] + kk][lane]);
      float E = 0.f;
      for (int kk = 0; kk < GK[g]; ++kk) {
        float e = __expf((lred[GB[g] + kk][lane] - mx) * scale);
        lred[GB[g] + kk][lane] = e;
        E += e;
      }
      const float inv = 1.f / E;
      for (int kk = 0; kk < GK[g]; ++kk) lred[GB[g] + kk][lane] *= inv;
    }
  }
  __syncthreads();

  // ---- phase 2: out[16 x 2560] = C[16 x 128] @ Btilde[128 x 2560] ----
  {
    s16x8 af2[4];
    #pragma unroll
    for (int s = 0; s < 4; ++s) {
      const int kbase = s * 32 + ko;
      s16x8 f;
      #pragma unroll
      for (int j = 0; j < 8; ++j) f[j] = f2bf(lred[kbase + j][lane15]);
      af2[s] = f;
    }

    const int orow0 = r0 + ((lane >> 4) << 2);
    float* obase = out + (size_t)orow0 * (5 * D) + lane15;

    phase2_group<0>(af2, mptb, obase, w, lane15, ko);
    phase2_group<1>(af2, mptb, obase, w, lane15, ko);
    phase2_group<2>(af2, mptb, obase, w, lane15, ko);
    phase2_group<3>(af2, mptb, obase, w, lane15, ko);
    phase2_group<4>(af2, mptb, obase, w, lane15, ko);
  }
}

extern "C" void kernel_launch(void* const* d_in, const int* in_sizes, int n_in,
                              void* d_out, int out_size, void* d_ws, size_t ws_size,
                              hipStream_t stream) {
  const float* x  = (const float*)d_in[0];
  const float* P0 = (const float*)d_in[1];  // gender [2,512]
  const float* P1 = (const float*)d_in[2];  // hair   [15,512]
  const float* P2 = (const float*)d_in[3];  // top    [40,512]
  const float* P3 = (const float*)d_in[4];  // pants  [40,512]
  const float* P4 = (const float*)d_in[5];  // shoes  [24,512]
  float* out = (float*)d_out;

  unsigned short* pnb  = (unsigned short*)d_ws;        // 128*512  u16 = 128 KiB
  unsigned short* mptb = pnb + 128 * 512;              // 2560*128 u16 = 640 KiB
  float* invn = (float*)(mptb + 2560 * 128);           // 121 floats

  prep_norms<<<dim3(121), dim3(64), 0, stream>>>(P0, P1, P2, P3, P4, invn);
  prep_pnb<<<dim3(256), dim3(256), 0, stream>>>(P0, P1, P2, P3, P4, invn, pnb);
  prep_mpt<<<dim3(1280), dim3(256), 0, stream>>>(P0, P1, P2, P3, P4, mptb);
  fused_main<<<dim3(2048), dim3(256), 0, stream>>>(x, pnb, mptb, out);
}

// Round 8
// 119.002 us; speedup vs baseline: 1.6257x; 1.6257x over previous
//
#include <hip/hip_runtime.h>
#include <hip/hip_bf16.h>
#include <math.h>

// CerberusSemanticIDBranch — fused prototype-softmax-affinity kernel for MI355X.
//
// out[r,g,:] = (e_g @ M'_g) / sum(e_g),  e_k = exp(l_k - max_g),
// l_k = (x_r . Pn_k) / ((||x_r||+1e-6) * tau),  Pn_k = P_k/(||P_k||+1e-6),
// M'_g = A_g @ P_g / (rowsum(A_g)+1e-6)   (rowsum(A) is constant per group).
//
// Round 8: round-6 geometry (512 blocks x 8 waves x 64 rows — best so far);
// attack the memory-TRANSACTION bottleneck:
//  (a) B matrices stored fragment-linear (pnbf/mptbf): each MFMA B-load is
//      base + lane*16B = one contiguous 1KB wave load, vs 16x64B gather.
//  (b) phase 2 works in 64-col strips; C-fragments bounce through a per-wave
//      LDS tile and are stored as float4 with 16 contiguous lanes -> 256B
//      full-line store segments (round 6: 64B half-line scatter; stores were
//      ~5.2M partial-line transactions = the modeled ~100+ us wall).
//  (c) store-bounce buffer aliases lred (dead after A-frag build) -> LDS ~35KB.

constexpr int D    = 512;
constexpr int KTOT = 121;
constexpr float TAU = 0.07f;

constexpr int GB[5]  = {0, 2, 17, 57, 97};   // group base row in concat [121] layout
constexpr int GK[5]  = {2, 15, 40, 40, 24};  // prototypes per group
constexpr int GD2[5] = {1, 3, 5, 5, 4};      // second attribute cardinality
constexpr int GNA[5] = {1, 2, 2, 2, 2};      // number of attributes
constexpr int KS0[5] = {0, 0, 0, 1, 3};      // first live 32-wide kstep of group
constexpr int KS1[5] = {1, 1, 2, 4, 4};      // one past last live kstep

using f32x4 = __attribute__((ext_vector_type(4))) float;
using s16x8 = __attribute__((ext_vector_type(8))) short;

__device__ __forceinline__ const float* pick(int k,
    const float* P0, const float* P1, const float* P2, const float* P3, const float* P4,
    int* kl) {
  if (k < 2)  { *kl = k;      return P0; }
  if (k < 17) { *kl = k - 2;  return P1; }
  if (k < 57) { *kl = k - 17; return P2; }
  if (k < 97) { *kl = k - 57; return P3; }
  *kl = k - 97; return P4;
}

__device__ __forceinline__ short f2bf(float f) {
  __hip_bfloat16 h = __float2bfloat16(f);   // RTNE
  return *reinterpret_cast<short*>(&h);
}

// ---- prep 1: inverse norms of the 121 prototype rows --------------------
__global__ void prep_norms(const float* __restrict__ P0, const float* __restrict__ P1,
                           const float* __restrict__ P2, const float* __restrict__ P3,
                           const float* __restrict__ P4, float* __restrict__ invn) {
  int k = blockIdx.x;  // 0..120
  int kl; const float* P = pick(k, P0, P1, P2, P3, P4, &kl);
  const float* row = P + (size_t)kl * D;
  float s = 0.f;
  for (int d = threadIdx.x; d < D; d += 64) { float v = row[d]; s += v * v; }
  #pragma unroll
  for (int m = 1; m < 64; m <<= 1) s += __shfl_xor(s, m);
  if (threadIdx.x == 0) invn[k] = 1.f / (sqrtf(s) + 1e-6f);
}

// ---- prep 2: pnbf = fragment-linear bf16 normalized prototypes ----------
// Block (ct 0..7, s 0..15) of 512 u16: pnbf[(ct*16+s)*512 + lane*8 + j]
//   = Pn[col = ct*16 + (lane&15)][k = s*32 + (lane>>4)*8 + j]  (col>=121 -> 0)
__global__ void prep_pnbf(const float* __restrict__ P0, const float* __restrict__ P1,
                          const float* __restrict__ P2, const float* __restrict__ P3,
                          const float* __restrict__ P4, const float* __restrict__ invn,
                          unsigned short* __restrict__ pnbf) {
  int idx = blockIdx.x * 256 + threadIdx.x;  // 128*512 = 65536
  int blk = idx >> 9, e = idx & 511;
  int lane = e >> 3, j = e & 7;
  int ct = blk >> 4, s = blk & 15;
  int col = ct * 16 + (lane & 15);
  int k   = s * 32 + (lane >> 4) * 8 + j;
  float v = 0.f;
  if (col < KTOT) {
    int kl; const float* P = pick(col, P0, P1, P2, P3, P4, &kl);
    v = P[(size_t)kl * D + k] * invn[col];
  }
  pnbf[idx] = (unsigned short)f2bf(v);
}

// ---- prep 3: mptbf = fragment-linear bf16 block-diag (A@P/rowsum)^T -----
// Block (c 0..159, ks 0..3) of 512 u16: mptbf[(c*4+ks)*512 + lane*8 + j]
//   = Mtilde[k = ks*32 + (lane>>4)*8 + j][gd = c*16 + (lane&15)],
// Mtilde[k][gd] nonzero only for k in [GB[g], GB[g]+GK[g]), g = gd>>9.
__global__ void prep_mptbf(const float* __restrict__ P0, const float* __restrict__ P1,
                           const float* __restrict__ P2, const float* __restrict__ P3,
                           const float* __restrict__ P4, unsigned short* __restrict__ mptbf) {
  int idx = blockIdx.x * 256 + threadIdx.x;  // 640*512 = 327680
  int blk = idx >> 9, e = idx & 511;
  int lane = e >> 3, j = e & 7;
  int c = blk >> 2, ks = blk & 3;
  int gd = c * 16 + (lane & 15);
  int k  = ks * 32 + (lane >> 4) * 8 + j;
  int g = gd >> 9, d = gd & (D - 1);
  float v = 0.f;
  if (k >= GB[g] && k < GB[g] + GK[g]) {
    int kl = k - GB[g];
    const float* P = (g == 0) ? P0 : (g == 1) ? P1 : (g == 2) ? P2 : (g == 3) ? P3 : P4;
    int d2 = GD2[g], na = GNA[g], K = GK[g];
    int a1 = kl / d2, a2 = kl % d2;
    float s = 0.f, m = 0.f;
    for (int jj = 0; jj < K; jj++) {
      float aff;
      if (na == 1) {
        aff = (jj == kl) ? 1.f : 0.f;
      } else {
        int b1 = jj / d2, b2 = jj % d2;
        aff = 0.5f * (float)((a1 == b1) + (a2 == b2));
      }
      s += aff;
      m += aff * P[(size_t)jj * D + d];
    }
    v = m / (s + 1e-6f);
  }
  mptbf[idx] = (unsigned short)f2bf(v);
}

// ---- phase 2 per-group body: all fragment indices compile-time ----------
// Wave handles 4 strips (64 cols each) of group G: s = G*8 + i*2 + ch.
// C-frags -> per-wave LDS tile (16 rows x 64 cols, stride 68) -> float4
// stores with 16 contiguous lanes = 256B full-line segments.
template <int G>
__device__ __forceinline__ void phase2_group(
    const s16x8 (&af2)[4], const unsigned short* __restrict__ mptbf,
    float* __restrict__ ob, float* __restrict__ obase, int ch, int lane) {
  const int l15 = lane & 15, hi = lane >> 4;
  #pragma unroll 1
  for (int i = 0; i < 4; ++i) {
    const int s = G * 8 + i * 2 + ch;          // strip: cols [64s, 64s+64)
    const unsigned short* bp = mptbf + (size_t)(s * 4) * 4 * 512 + lane * 8;
    f32x4 a0 = (f32x4){0.f, 0.f, 0.f, 0.f}, a1 = a0, a2 = a0, a3 = a0;
    #pragma unroll
    for (int ks = KS0[G]; ks < KS1[G]; ++ks) {  // constexpr -> af2[ks] static
      s16x8 b0 = *(const s16x8*)(bp + (0 * 4 + ks) * 512);
      s16x8 b1 = *(const s16x8*)(bp + (1 * 4 + ks) * 512);
      s16x8 b2 = *(const s16x8*)(bp + (2 * 4 + ks) * 512);
      s16x8 b3 = *(const s16x8*)(bp + (3 * 4 + ks) * 512);
      a0 = __builtin_amdgcn_mfma_f32_16x16x32_bf16(af2[ks], b0, a0, 0, 0, 0);
      a1 = __builtin_amdgcn_mfma_f32_16x16x32_bf16(af2[ks], b1, a1, 0, 0, 0);
      a2 = __builtin_amdgcn_mfma_f32_16x16x32_bf16(af2[ks], b2, a2, 0, 0, 0);
      a3 = __builtin_amdgcn_mfma_f32_16x16x32_bf16(af2[ks], b3, a3, 0, 0, 0);
    }
    // scatter C-frags into LDS: row = hi*4+j, col = t*16 + l15 (<=2-way banks)
    #pragma unroll
    for (int j = 0; j < 4; ++j) {
      const int row = hi * 4 + j;
      ob[row * 68 +  0 + l15] = a0[j];
      ob[row * 68 + 16 + l15] = a1[j];
      ob[row * 68 + 32 + l15] = a2[j];
      ob[row * 68 + 48 + l15] = a3[j];
    }
    // read back row-major and store: 4 rows x 256B contiguous per instr
    float* gp = obase + (size_t)s * 64 + l15 * 4;
    #pragma unroll
    for (int i2 = 0; i2 < 4; ++i2) {
      const int row = i2 * 4 + hi;
      float4 v = *(float4*)&ob[row * 68 + l15 * 4];
      *(float4*)(gp + (size_t)row * (5 * D)) = v;
    }
  }
}

// ---- main fused kernel --------------------------------------------------
// 512 blocks x 512 threads (8 waves); block owns 64 rows. Phase 1: wave
// (w&3) = 16-row slab, (w>>2) = 64-col half, 16 ksteps x 4 MFMA. Phase 2:
// wave takes 4 strips per group (parity w>>2).
__global__ __launch_bounds__(512, 4) void fused_main(
    const float* __restrict__ x, const unsigned short* __restrict__ pnbf,
    const unsigned short* __restrict__ mptbf, float* __restrict__ out) {
  // smem serves as lred[128][65] (phases 1-sm-A-build), then per-wave
  // 16x68 store-bounce tiles (phase 2). 8704 f32 = 34816 B.
  __shared__ __align__(16) float smem[8704];
  __shared__ float xsqs[64];
  float (*lred)[65] = (float (*)[65])smem;

  const int tid  = threadIdx.x;
  const int lane = tid & 63;
  const int w    = __builtin_amdgcn_readfirstlane(tid >> 6);
  const int r0   = blockIdx.x * 64;

  const int wr = (w & 3) << 4;   // wave's 16-row slab (block-local)
  const int ch = w >> 2;         // column half / strip parity
  const int ko = (lane >> 4) << 3;

  // ---- phase 1: 16x64 logit tile via MFMA, K = 512 ----
  {
    const int arow = wr + (lane & 15);
    const float* xrow = x + (size_t)(r0 + arow) * D + ko;

    f32x4 acc[4];
    #pragma unroll
    for (int t = 0; t < 4; ++t) acc[t] = (f32x4){0.f, 0.f, 0.f, 0.f};
    float xsq = 0.f;

    #pragma unroll 4
    for (int s = 0; s < 16; ++s) {
      float4 a0 = *(const float4*)(xrow + s * 32);
      float4 a1 = *(const float4*)(xrow + s * 32 + 4);
      xsq += a0.x * a0.x + a0.y * a0.y + a0.z * a0.z + a0.w * a0.w
           + a1.x * a1.x + a1.y * a1.y + a1.z * a1.z + a1.w * a1.w;
      s16x8 af;
      af[0] = f2bf(a0.x); af[1] = f2bf(a0.y); af[2] = f2bf(a0.z); af[3] = f2bf(a0.w);
      af[4] = f2bf(a1.x); af[5] = f2bf(a1.y); af[6] = f2bf(a1.z); af[7] = f2bf(a1.w);
      #pragma unroll
      for (int t = 0; t < 4; ++t) {
        // fragment-linear B: one contiguous 1KB wave load
        s16x8 bfv = *(const s16x8*)(pnbf + (size_t)(((ch << 2) + t) * 16 + s) * 512 + lane * 8);
        acc[t] = __builtin_amdgcn_mfma_f32_16x16x32_bf16(af, bfv, acc[t], 0, 0, 0);
      }
    }

    // ||x||^2: lanes {l, l^16, l^32, l^48} share the same A-row
    xsq += __shfl_xor(xsq, 16);
    xsq += __shfl_xor(xsq, 32);
    if (w < 4 && lane < 16) xsqs[wr + lane] = xsq;

    // dump C-frags: col = lane&15, row = (lane>>4)*4 + j
    const int drow = wr + ((lane >> 4) << 2);
    #pragma unroll
    for (int t = 0; t < 4; ++t) {
      const int col = (ch << 6) + (t << 4) + (lane & 15);
      #pragma unroll
      for (int j = 0; j < 4; ++j) lred[col][drow + j] = acc[t][j];
    }
  }
  __syncthreads();

  // ---- softmax per group (wave g handles group g; lane = row), 3-pass ----
  if (w < 5) {
    const int g = w;
    const float scale = 1.f / ((sqrtf(xsqs[lane]) + 1e-6f) * TAU);
    float mx = -1e30f;
    for (int kk = 0; kk < GK[g]; ++kk)
      mx = fmaxf(mx, lred[GB[g] + kk][lane]);
    float E = 0.f;
    for (int kk = 0; kk < GK[g]; ++kk) {
      float e = __expf((lred[GB[g] + kk][lane] - mx) * scale);
      lred[GB[g] + kk][lane] = e;
      E += e;
    }
    const float inv = 1.f / E;
    for (int kk = 0; kk < GK[g]; ++kk) lred[GB[g] + kk][lane] *= inv;
  }
  __syncthreads();

  // ---- A-frags for phase 2 (lred still live) ----
  s16x8 af2[4];
  {
    const int ar = wr + (lane & 15);
    #pragma unroll
    for (int s = 0; s < 4; ++s) {
      const int kbase = s * 32 + ko;
      s16x8 f;
      #pragma unroll
      for (int j = 0; j < 8; ++j) f[j] = f2bf(lred[kbase + j][ar]);
      af2[s] = f;
    }
  }
  __syncthreads();   // lred dead; smem becomes per-wave store-bounce tiles

  // ---- phase 2: out[64 x 2560] = C @ Btilde, strip-wise full-line stores --
  {
    float* ob    = smem + w * (16 * 68);                  // per-wave 16x68 tile
    float* obase = out + (size_t)(r0 + wr) * (5 * D);     // slab's global base

    phase2_group<0>(af2, mptbf, ob, obase, ch, lane);
    phase2_group<1>(af2, mptbf, ob, obase, ch, lane);
    phase2_group<2>(af2, mptbf, ob, obase, ch, lane);
    phase2_group<3>(af2, mptbf, ob, obase, ch, lane);
    phase2_group<4>(af2, mptbf, ob, obase, ch, lane);
  }
}

extern "C" void kernel_launch(void* const* d_in, const int* in_sizes, int n_in,
                              void* d_out, int out_size, void* d_ws, size_t ws_size,
                              hipStream_t stream) {
  const float* x  = (const float*)d_in[0];
  const float* P0 = (const float*)d_in[1];  // gender [2,512]
  const float* P1 = (const float*)d_in[2];  // hair   [15,512]
  const float* P2 = (const float*)d_in[3];  // top    [40,512]
  const float* P3 = (const float*)d_in[4];  // pants  [40,512]
  const float* P4 = (const float*)d_in[5];  // shoes  [24,512]
  float* out = (float*)d_out;

  unsigned short* pnbf  = (unsigned short*)d_ws;       // 128*512  u16 = 128 KiB
  unsigned short* mptbf = pnbf + 128 * 512;            // 640*512  u16 = 640 KiB
  float* invn = (float*)(mptbf + 640 * 512);           // 121 floats

  prep_norms<<<dim3(121), dim3(64), 0, stream>>>(P0, P1, P2, P3, P4, invn);
  prep_pnbf<<<dim3(256), dim3(256), 0, stream>>>(P0, P1, P2, P3, P4, invn, pnbf);
  prep_mptbf<<<dim3(1280), dim3(256), 0, stream>>>(P0, P1, P2, P3, P4, mptbf);
  fused_main<<<dim3(512), dim3(512), 0, stream>>>(x, pnbf, mptbf, out);
}